// Round 1
// baseline (174.974 us; speedup 1.0000x reference)
//
#include <hip/hip_runtime.h>
#include <stdint.h>

// Problem constants (fixed by reference setup_inputs):
//   qt:     (H=25920, S=64, D=64) f32
//   k:      (H, 1, D) f32          -- DEAD: softmax over singleton axis == 1
//   scaleb: (H, 1, 1) f32          -- DEAD: same reason
//   biasb:  (H, 1, 1) f32          -- zeros; a5 = dropout_mask * biasb == 0
// out = qt + broadcast(a5) ; a5[h,s] = (bernoulli_keep ? 1/keep : 0) * biasb[h]
//
// Memory-bound: ~850 MB traffic -> ~135 us roofline @ 6.3 TB/s.

#define NH 25920
#define NS 64
#define ND 64

__device__ __forceinline__ uint32_t rotl32(uint32_t x, int n) {
  return (x << n) | (x >> (32 - n));
}

// JAX threefry2x32 with key = jax.random.key(42) -> (k0,k1) = (0,42).
__device__ __forceinline__ void threefry2x32_0_42(uint32_t x0, uint32_t x1,
                                                  uint32_t& y0, uint32_t& y1) {
  const uint32_t ks0 = 0u;
  const uint32_t ks1 = 42u;
  const uint32_t ks2 = 0u ^ 42u ^ 0x1BD11BDAu;
  x0 += ks0; x1 += ks1;
#define RND(r) { x0 += x1; x1 = rotl32(x1, (r)); x1 ^= x0; }
  RND(13) RND(15) RND(26) RND(6)
  x0 += ks1; x1 += ks2 + 1u;
  RND(17) RND(29) RND(16) RND(24)
  x0 += ks2; x1 += ks0 + 2u;
  RND(13) RND(15) RND(26) RND(6)
  x0 += ks0; x1 += ks1 + 3u;
  RND(17) RND(29) RND(16) RND(24)
  x0 += ks1; x1 += ks2 + 4u;
  RND(13) RND(15) RND(26) RND(6)
  x0 += ks2; x1 += ks0 + 5u;
#undef RND
  y0 = x0; y1 = x1;
}

__global__ void __launch_bounds__(256)
fused_residual_kernel(const float4* __restrict__ qt4,
                      const float* __restrict__ biasb,
                      float4* __restrict__ out4,
                      int total4) {
  const float keep = 0.2021470392102155f;
  const int64_t stride = (int64_t)gridDim.x * blockDim.x;
  for (int64_t i = (int64_t)blockIdx.x * blockDim.x + threadIdx.x; i < total4;
       i += stride) {
    float4 v = qt4[i];
    // row index (h*NS + s); each row is ND=64 floats = 16 float4
    const int64_t row = i >> 4;
    const int h = (int)(row >> 6);  // row / NS
    const float b = biasb[h];
    float add = 0.0f;
    if (b != 0.0f) {
      // Exact JAX bernoulli(key(42), keep, (NH,NS,1)) mask for this row.
      // random_bits: counts = iota(n); block i = (counts[i], counts[i+n/2]);
      // out[i] = y0 of block i (i < n/2), out[i+n/2] = y1 of block i.
      const uint32_t n = (uint32_t)(NH * NS);
      const uint32_t half = n >> 1;
      const uint32_t g = (uint32_t)row;
      uint32_t x0, x1, y0, y1;
      const bool hi = (g >= half);
      if (hi) { x0 = g - half; x1 = g; } else { x0 = g; x1 = g + half; }
      threefry2x32_0_42(x0, x1, y0, y1);
      const uint32_t bits = hi ? y1 : y0;
      const float u = __uint_as_float((bits >> 9) | 0x3F800000u) - 1.0f;
      if (u < keep) add = b / keep;  // a3 == 1 (softmax over singleton)
    }
    v.x += add; v.y += add; v.z += add; v.w += add;
    out4[i] = v;
  }
}

extern "C" void kernel_launch(void* const* d_in, const int* in_sizes, int n_in,
                              void* d_out, int out_size, void* d_ws, size_t ws_size,
                              hipStream_t stream) {
  const float4* qt4 = (const float4*)d_in[0];
  // d_in[1] = k (unused), d_in[2] = scaleb (unused)
  const float* biasb = (const float*)d_in[3];
  float4* out4 = (float4*)d_out;

  const int total4 = (NH * NS * ND) / 4;  // 26,542,080
  const int block = 256;
  const int grid = 4096;  // grid-stride; ~25 float4 iters/thread
  fused_residual_kernel<<<grid, block, 0, stream>>>(qt4, biasb, out4, total4);
}